// Round 3
// baseline (823.050 us; speedup 1.0000x reference)
//
#include <hip/hip_runtime.h>
#include <hip/hip_bf16.h>

// 3-step Euler residual block via bf16 MFMA implicit-GEMM.
//   t = relu(conv(x,w1)+b1); x += (1/3)*(conv(t,w2)+b2); x3 times; out = relu(x)
// B=16, C=128, H=W=128. Activations NHWC bf16 in ws (XB = x state, T = t).
// Block = one (b,y) output row: 128 oc x 128 pix, 4 waves of 64x64.
//
// R5: counted-vmcnt pipeline (T3+T4+T5). R2-R4 all pinned at MfmaUtil 27.5%
// regardless of staging/occupancy -> the per-step __syncthreads vmcnt(0) drain
// was the invariant cost (~200+ cyc exposed L2 latency per step). Now:
//   - loop (ky, kq, kx): input row split into 4 K=32 slices [130x32], dbuf'd,
//     prefetched one 3-step group ahead (~3 steps of latency budget).
//   - weights triple-buffered (3x8KB), prefetched 2 steps ahead.
//   - raw s_barrier + per-wave exact ledger: vmcnt(2) at kx==0 else vmcnt(4).
//     Loads NEVER drain to 0 in the loop (m218: counted-vs-drain0 = +38-73%).
//   - setprio(1) around the MFMA cluster (T5: pays on phase-split schedules).
// LDS = 2*130*32*2 + 3*128*32*2 = 41.2 KB -> 3 blocks/CU.

#define BATCH 16
#define CH    128
#define HH    128
#define WW    128
#define H_STEP (1.0f/3.0f)

typedef short bf16x8 __attribute__((ext_vector_type(8)));
typedef float f32x4  __attribute__((ext_vector_type(4)));

__device__ __forceinline__ float bf2f(unsigned short u) {
    union { unsigned int i; float f; } c; c.i = ((unsigned int)u) << 16; return c.f;
}
__device__ __forceinline__ unsigned short f2bf(float f) {
    union { float f; unsigned int i; } c; c.f = f;
    unsigned int i = c.i;
    return (unsigned short)((i + 0x7FFFu + ((i >> 16) & 1u)) >> 16);  // RNE
}

// async 16B global->LDS. lptr must be wave-uniform; lane l lands at lptr+16*l.
__device__ __forceinline__ void gload16(const unsigned short* g, unsigned short* l) {
    __builtin_amdgcn_global_load_lds(
        (const __attribute__((address_space(1))) unsigned int*)g,
        (__attribute__((address_space(3))) unsigned int*)l, 16, 0, 0);
}

// ---------------- initial transpose: x0 NCHW fp32 -> XB NHWC bf16 --------------
__global__ __launch_bounds__(256)
void transpose_x(const float* __restrict__ x, unsigned short* __restrict__ xb)
{
    __shared__ unsigned short s[128 * 132];   // [ci][x], +4 pad
    const int tid = threadIdx.x;
    const int bz  = blockIdx.x;               // 0..2047 = (b,y)
    const int b = bz >> 7, y = bz & 127;

    #pragma unroll
    for (int it = 0; it < 16; ++it) {
        int idx = it * 256 + tid;             // 0..4095
        int ci = idx >> 5, xq = idx & 31;
        float4 v = *(const float4*)&x[(((size_t)b * CH + ci) * HH + y) * WW + xq * 4];
        uint2 p;
        p.x = (unsigned int)f2bf(v.x) | ((unsigned int)f2bf(v.y) << 16);
        p.y = (unsigned int)f2bf(v.z) | ((unsigned int)f2bf(v.w) << 16);
        *(uint2*)&s[ci * 132 + xq * 4] = p;
    }
    __syncthreads();
    #pragma unroll
    for (int it = 0; it < 8; ++it) {
        int idx = it * 256 + tid;             // 0..2047
        int xx = idx >> 4, cc = idx & 15;
        unsigned short t[8];
        #pragma unroll
        for (int k = 0; k < 8; ++k) t[k] = s[(cc * 8 + k) * 132 + xx];
        uint4 p;
        p.x = (unsigned int)t[0] | ((unsigned int)t[1] << 16);
        p.y = (unsigned int)t[2] | ((unsigned int)t[3] << 16);
        p.z = (unsigned int)t[4] | ((unsigned int)t[5] << 16);
        p.w = (unsigned int)t[6] | ((unsigned int)t[7] << 16);
        *(uint4*)&xb[((size_t)(b * HH + y) * WW + xx) * CH + cc * 8] = p;
    }
}

// --------------- weight convert: OIHW fp32 -> [tap][oc][ci] bf16 ---------------
__global__ __launch_bounds__(256)
void convert_w(const float* __restrict__ w, unsigned short* __restrict__ wb)
{
    int idx = blockIdx.x * 256 + threadIdx.x;   // 0..16383 = oc*128+ci
    #pragma unroll
    for (int t = 0; t < 9; ++t)
        wb[t * 16384 + idx] = f2bf(w[(size_t)idx * 9 + t]);
}

// ------------------------------ conv3x3 MFMA ----------------------------------
// MODE 0: outb = bf16(relu(acc + bias))                       (conv1 -> T)
// MODE 1: outb = bf16(res + h*(acc + bias))                   (conv2 -> XB, in place)
// MODE 2: outf = relu(res + h*(acc + bias)) fp32 NCHW         (final conv2 -> d_out)
template<int MODE>
__global__ __launch_bounds__(256, 3)
void conv_mfma(const unsigned short* __restrict__ in,   // NHWC bf16
               const unsigned short* __restrict__ wb,   // [9][128][128] bf16
               const float* __restrict__ bias,
               const unsigned short* resb,              // NHWC bf16 (may alias outb)
               unsigned short* outb,                    // NHWC bf16
               float* __restrict__ outf)                // NCHW fp32
{
    // Linear LDS dests (gload_lds requirement); bank spread via XOR-chunk
    // swizzle baked into the per-lane GLOBAL source address and the read addr.
    // Both tiles: slot (row, c) holds 16B k-chunk (c ^ (row&3)) of that row.
    __shared__ unsigned short s_is[2][130 * 32];     // input K=32 slices, dbuf, 16.6 KB
    __shared__ unsigned short s_w [3][128 * 32];     // weight K=32 tiles, 3-deep, 24 KB

    const int tid = threadIdx.x;
    const int bz0 = blockIdx.x;
    const int bz  = ((bz0 & 7) << 8) | (bz0 >> 3);   // XCD-chunked swizzle (2048%8==0)
    const int b = bz >> 7, y = bz & 127;

    const int lane = tid & 63;
    const int wid  = tid >> 6;
    const int woc0 = (wid >> 1) * 64;
    const int wpx0 = (wid & 1) * 64;
    const int n16  = lane & 15;
    const int q    = lane >> 4;

    // staging decomposition: 4 lanes per 64B row, 16 rows per wave per call
    const int srow = lane >> 2;          // 0..15
    const int slot = lane & 3;           // 16B chunk slot 0..3

    const int kylo = (y == 0)      ? 1 : 0;
    const int kyhi = (y == HH - 1) ? 1 : 2;
    const int nky  = kyhi - kylo + 1;
    const int NG   = nky * 4;                        // input-slice groups
    const int NS   = NG * 3;                         // total steps

    f32x4 acc[4][4];
    #pragma unroll
    for (int i = 0; i < 4; ++i)
        #pragma unroll
        for (int j = 0; j < 4; ++j) acc[i][j] = (f32x4)0.0f;

    // stage one weight K=32 tile (128 oc x 32 ci = 8 KB), 2 gload16/wave
    auto stage_w = [&](int tap, int kq, int buf) {
        const unsigned short* wt = wb + tap * 16384 + kq * 32;
        #pragma unroll
        for (int c = 0; c < 2; ++c) {
            int row = (wid * 2 + c) * 16 + srow;             // oc 0..127
            const unsigned short* src = wt + row * 128 + ((slot ^ (row & 3)) << 3);
            gload16(src, &s_w[buf][(wid * 2 + c) * 512]);
        }
    };
    // stage one input K=32 slice (rows 1..128; halos fixed), 2 gload16/wave
    auto stage_is = [&](int gy, int kq, int buf) {
        const size_t inrow = ((size_t)(b * HH + gy) * WW) * CH + kq * 32;
        #pragma unroll
        for (int c = 0; c < 2; ++c) {
            int r   = (c * 4 + wid) * 16 + srow;             // x 0..127
            int swz = (r + 1) & 3;                           // LDS row = x+1
            const unsigned short* src = in + inrow + (size_t)r * CH + ((slot ^ swz) << 3);
            gload16(src, &s_is[buf][((c * 4 + wid) * 16 + 1) * 32]);
        }
    };

    // ---- prologue: issue order defines the vmcnt ledger: w(0), is(0), w(1) ----
    stage_w(kylo * 3 + 0, 0, 0);                 // step 0 tile
    stage_is(y + kylo - 1, 0, 0);                // group 0 slice
    stage_w(kylo * 3 + 1, 0, 1);                 // step 1 tile
    // zero halo rows (x=-1, x=128) of both slice buffers, once
    if (tid < 16) {
        int bfi = tid >> 3, rr = ((tid >> 2) & 1) ? 129 : 0, cc = tid & 3;
        uint4 z = {0u, 0u, 0u, 0u};
        *(uint4*)&s_is[bfi][rr * 32 + cc * 8] = z;
    }
    asm volatile("s_waitcnt lgkmcnt(0)" ::: "memory");   // halo writes visible

    const int NSm1 = NS - 1;
    for (int s = 0; s < NS; ++s) {
        const int g   = s / 3;
        const int kx  = s - g * 3;               // == s%3 == current wbuf index
        const int kyi = g >> 2;
        const int ig  = g & 1;                   // current input slice buffer

        // gate: own prefetches for THIS step landed; 2 (kx==0) or 4 newer stay
        // in flight across the barrier (never drain to 0 in the loop).
        if (kx == 0) asm volatile("s_waitcnt vmcnt(2)" ::: "memory");
        else         asm volatile("s_waitcnt vmcnt(4)" ::: "memory");
        asm volatile("s_barrier" ::: "memory");  // cross-wave visibility + reuse safety

        // prefetch weights for s+2 (buffer from unclamped index; coords clamped
        // at the tail -> redundant L2-hit reload, keeps the ledger uniform)
        {
            int wb2 = (kx == 0) ? 2 : (kx - 1);  // (s+2)%3
            int s2  = s + 2; if (s2 > NSm1) s2 = NSm1;
            int g2  = s2 / 3, kx2 = s2 - g2 * 3;
            stage_w((kylo + (g2 >> 2)) * 3 + kx2, g2 & 3, wb2);
        }
        // prefetch next input slice at the start of each 3-step group
        if (kx == 0) {
            int gn = g + 1; if (gn > NG - 1) gn = NG - 1;
            stage_is(y + kylo + (gn >> 2) - 1, gn & 3, (g + 1) & 1);
        }

        // K=32 compute: 8 ds_read_b128 + 16 MFMA
        bf16x8 af[4], bfr[4];
        #pragma unroll
        for (int i = 0; i < 4; ++i) {
            int row = woc0 + i * 16 + n16;
            af[i] = *(const bf16x8*)&s_w[kx][row * 32 + ((q ^ (row & 3)) << 3)];
        }
        #pragma unroll
        for (int j = 0; j < 4; ++j) {
            int rowb = wpx0 + j * 16 + n16 + kx;             // pixel + kx - 1, +1 halo
            bfr[j] = *(const bf16x8*)&s_is[ig][rowb * 32 + ((q ^ (rowb & 3)) << 3)];
        }
        __builtin_amdgcn_s_setprio(1);
        #pragma unroll
        for (int i = 0; i < 4; ++i)
            #pragma unroll
            for (int j = 0; j < 4; ++j)
                acc[i][j] = __builtin_amdgcn_mfma_f32_16x16x32_bf16(
                    af[i], bfr[j], acc[i][j], 0, 0, 0);
        __builtin_amdgcn_s_setprio(0);
    }

    // ------------------------------ epilogue ---------------------------------
    const int ybase = (b * HH + y) * WW;
    if (MODE == 0 || MODE == 1) {
        #pragma unroll
        for (int j = 0; j < 4; ++j) {
            int x = wpx0 + j * 16 + n16;
            size_t pbase = (size_t)(ybase + x) * CH;
            #pragma unroll
            for (int i = 0; i < 4; ++i) {
                int oc0 = woc0 + i * 16 + q * 4;
                float v0 = acc[i][j][0] + bias[oc0 + 0];
                float v1 = acc[i][j][1] + bias[oc0 + 1];
                float v2 = acc[i][j][2] + bias[oc0 + 2];
                float v3 = acc[i][j][3] + bias[oc0 + 3];
                if (MODE == 0) {
                    v0 = fmaxf(v0, 0.f); v1 = fmaxf(v1, 0.f);
                    v2 = fmaxf(v2, 0.f); v3 = fmaxf(v3, 0.f);
                } else {
                    uint2 rr = *(const uint2*)&resb[pbase + oc0];
                    v0 = bf2f((unsigned short)(rr.x & 0xffff)) + H_STEP * v0;
                    v1 = bf2f((unsigned short)(rr.x >> 16))    + H_STEP * v1;
                    v2 = bf2f((unsigned short)(rr.y & 0xffff)) + H_STEP * v2;
                    v3 = bf2f((unsigned short)(rr.y >> 16))    + H_STEP * v3;
                }
                uint2 po;
                po.x = (unsigned int)f2bf(v0) | ((unsigned int)f2bf(v1) << 16);
                po.y = (unsigned int)f2bf(v2) | ((unsigned int)f2bf(v3) << 16);
                *(uint2*)&outb[pbase + oc0] = po;
            }
        }
    } else {
        // fp32 NCHW out + final relu; residual still bf16 NHWC
        #pragma unroll
        for (int i = 0; i < 4; ++i) {
            #pragma unroll
            for (int r = 0; r < 4; ++r) {
                int oc = woc0 + i * 16 + q * 4 + r;
                float bv = bias[oc];
                size_t orow = ((size_t)(b * CH + oc) * HH + y) * WW;
                #pragma unroll
                for (int j = 0; j < 4; ++j) {
                    int x = wpx0 + j * 16 + n16;
                    float v = acc[i][j][r] + bv;
                    v = bf2f(resb[(size_t)(ybase + x) * CH + oc]) + H_STEP * v;
                    outf[orow + x] = fmaxf(v, 0.f);
                }
            }
        }
    }
}

// ------------------------------------------------------------------------------
extern "C" void kernel_launch(void* const* d_in, const int* in_sizes, int n_in,
                              void* d_out, int out_size, void* d_ws, size_t ws_size,
                              hipStream_t stream) {
    const float* x0 = (const float*)d_in[0];
    const float* w1 = (const float*)d_in[1];
    const float* b1 = (const float*)d_in[2];
    const float* w2 = (const float*)d_in[3];
    const float* b2 = (const float*)d_in[4];

    const size_t NELEM = (size_t)BATCH * CH * HH * WW;       // 33,554,432
    unsigned short* XB = (unsigned short*)d_ws;              // x state, NHWC bf16
    unsigned short* T  = XB + NELEM;                         // t,       NHWC bf16

    unsigned short* WB1;
    if (ws_size >= NELEM * 4 + 2 * 294912)
        WB1 = T + NELEM;
    else
        WB1 = (unsigned short*)d_in[0];                      // x0 dead after transpose
    unsigned short* WB2 = WB1 + 9 * 16384;

    dim3 block(256);
    dim3 gridRow(BATCH * HH);    // 2048: one block per (b, y)

    transpose_x<<<gridRow, block, 0, stream>>>(x0, XB);      // reads x0 first
    convert_w<<<dim3(64), block, 0, stream>>>(w1, WB1);      // then x0 may be clobbered
    convert_w<<<dim3(64), block, 0, stream>>>(w2, WB2);

    // step 1
    conv_mfma<0><<<gridRow, block, 0, stream>>>(XB, WB1, b1, nullptr, T, nullptr);
    conv_mfma<1><<<gridRow, block, 0, stream>>>(T, WB2, b2, XB, XB, nullptr);
    // step 2
    conv_mfma<0><<<gridRow, block, 0, stream>>>(XB, WB1, b1, nullptr, T, nullptr);
    conv_mfma<1><<<gridRow, block, 0, stream>>>(T, WB2, b2, XB, XB, nullptr);
    // step 3 (final relu, fp32 NCHW out)
    conv_mfma<0><<<gridRow, block, 0, stream>>>(XB, WB1, b1, nullptr, T, nullptr);
    conv_mfma<2><<<gridRow, block, 0, stream>>>(T, WB2, b2, XB, nullptr, (float*)d_out);
}